// Round 5
// baseline (718.205 us; speedup 1.0000x reference)
//
#include <hip/hip_runtime.h>
#include <hip/hip_bf16.h>
#include <hip/hip_fp16.h>

// Fused AdvancedHomeostaticCell, round 5: n-sliced block design.
// Block = 4 waves x 128 rows. Wave w owns n-slice [32w,32w+32): its weight
// slices live in REGISTERS (reused across 4 m-tiles); x staged once per block
// in swizzled LDS; h_raw exchanged through the same LDS region; all small
// params in LDS. Compute phase has zero global loads -> latency off the
// critical path.

typedef __attribute__((ext_vector_type(8)))  short short8;
typedef __attribute__((ext_vector_type(16))) float f32x16;

__device__ __forceinline__ unsigned short f2bf(float f) {   // prep kernels only
    union { float f; unsigned u; } v; v.f = f;
    unsigned r = v.u + 0x7fffu + ((v.u >> 16) & 1u);
    return (unsigned short)(r >> 16);
}
__device__ __forceinline__ float bf2f(unsigned hs) {
    union { unsigned u; float f; } v; v.u = hs << 16;
    return v.f;
}
__device__ __forceinline__ unsigned pk_bf16(float lo, float hi) {
    union { __hip_bfloat162 h; unsigned u; } c;
    c.h = __float22bfloat162_rn(make_float2(lo, hi));
    return c.u;
}
__device__ __forceinline__ unsigned pk_f16(float lo, float hi) {
    union { __half2 h; unsigned u; } c;
    c.h = __floats2half2_rn(lo, hi);
    return c.u;
}
__device__ __forceinline__ float lo_f16(unsigned u) {
    union { unsigned u; __half2 h; } c; c.u = u;
    return __low2float(c.h);
}
__device__ __forceinline__ float hi_f16(unsigned u) {
    union { unsigned u; __half2 h; } c; c.u = u;
    return __high2float(c.h);
}
__device__ __forceinline__ float rcp_fast(float x) { return __builtin_amdgcn_rcpf(x); }
__device__ __forceinline__ float exp2_fast(float x) { return __builtin_amdgcn_exp2f(x); }
__device__ __forceinline__ float sigm(float x) {
    return rcp_fast(1.0f + exp2_fast(-1.4426950408889634f * x));
}
__device__ __forceinline__ float tanh_fast(float x) {
    return 1.0f - 2.0f * rcp_fast(1.0f + exp2_fast(2.8853900817779268f * x));
}
__device__ __forceinline__ f32x16 mfma_bf16(short8 a, short8 b, f32x16 c) {
    return __builtin_amdgcn_mfma_f32_32x32x16_bf16(a, b, c, 0, 0, 0);
}

#define SWZ(r) ((unsigned)(((r) & 15) << 4))

// ---------- prep: fragment-major bf16 weights ------------------------------
// Wshuf element index = ((g*4 + jg)*8 + ks)*512 + lane*8 + e
//   g: 0=Wi, 1=Wf(x half), 2=Wslow+Wfast, 3=Wo ; jg: n-tile ; ks: k-tile
//   fragment value[e] = Wg[jg*32 + (lane&31)][ks*16 + (lane>>5)*8 + e]
__global__ void prep_weights(const float* __restrict__ Wi_w,
                             const float* __restrict__ Wf_w,
                             const float* __restrict__ Ws_w,
                             const float* __restrict__ Wfast_w,
                             const float* __restrict__ Wo_w,
                             unsigned short* __restrict__ Wshuf) {
    int gid = blockIdx.x * 256 + threadIdx.x;   // 0 .. 65535
    int e    = gid & 7;
    int lane = (gid >> 3) & 63;
    int ks   = (gid >> 9) & 7;
    int t    = gid >> 12;                       // g*4 + jg
    int g = t >> 2, jg = t & 3;
    int row = jg * 32 + (lane & 31);
    int k   = ks * 16 + (lane >> 5) * 8 + e;
    float v;
    if (g == 0)      v = Wi_w[row * 128 + k];
    else if (g == 1) v = Wf_w[row * 256 + k];
    else if (g == 2) v = Ws_w[row * 128 + k] + Wfast_w[row * 128 + k];
    else             v = Wo_w[row * 128 + k];
    Wshuf[gid] = f2bf(v);
}

// fbias[j] = Wf_b[j] + sum_k Wf_w[j][128+k] * h_prev[k]
__global__ void prep_fbias(const float* __restrict__ Wf_w,
                           const float* __restrict__ Wf_b,
                           const float* __restrict__ hp,
                           float* __restrict__ fbias) {
    int j = threadIdx.x;
    float s = Wf_b[j];
    for (int k = 0; k < 128; ++k) s += Wf_w[j * 256 + 128 + k] * hp[k];
    fbias[j] = s;
}

// ------------------------------ main fused kernel --------------------------
__global__ __launch_bounds__(256, 3)
void cell_main(const float* __restrict__ x,
               const float* __restrict__ hp,
               const float* __restrict__ Wi_b,
               const float* __restrict__ Ws_b,
               const float* __restrict__ Wo_b,
               const float* __restrict__ ln_g,
               const float* __restrict__ ln_b,
               const unsigned short* __restrict__ Wshuf,
               const float* __restrict__ fbias,
               float* __restrict__ out) {
    const int tid  = threadIdx.x;
    const int lane = tid & 63;
    const int w    = tid >> 6;          // wave id = n-slice index
    const int lm   = lane & 31;         // m-local (MFMA column) / weight row
    const int h    = lane >> 5;         // half-wave k-selector

    __shared__ __align__(16) char  xh[32768];          // x bf16 -> later h_raw
    __shared__ __align__(16) float prm[7 * 128];       // staged params
    __shared__ __align__(16) float red[4][4][32][2];   // [w][mt][lm][{sum,ssq}]

    const size_t row0 = (size_t)blockIdx.x * 128;

    // ---- phase A: stage x (bf16, swizzled rows of 256B) + params ----------
    {
        const float* xb = x + row0 * 128;
        #pragma unroll
        for (int it = 0; it < 16; ++it) {
            const int idx = it * 256 + tid;            // float4 index, coalesced
            const float4 v = *(const float4*)(xb + (size_t)idx * 4);
            const int r = idx >> 5;                    // local row
            const unsigned byteoff = ((unsigned)(r * 256 + (idx & 31) * 8)) ^ SWZ(r);
            *(uint2*)(xh + byteoff) = make_uint2(pk_bf16(v.x, v.y), pk_bf16(v.z, v.w));
        }
        if (tid < 224) {                               // 7 param arrays x 128 f32
            const int a = tid >> 5, e4 = (tid & 31) * 4;
            float4 v;
            switch (a) {
                case 0: v = *(const float4*)(Wi_b + e4); break;
                case 1: v = *(const float4*)(Ws_b + e4); break;
                case 2: v = *(const float4*)(fbias + e4); break;
                case 3: v = *(const float4*)(hp + e4); break;
                case 4: v = *(const float4*)(Wo_b + e4); break;
                case 5: v = *(const float4*)(ln_g + e4); break;
                default: v = *(const float4*)(ln_b + e4); break;
            }
            *(float4*)(prm + a * 128 + e4) = v;
        }
    }
    __syncthreads();

    // fragment read: k = ks*16 + h*8 + 0..7 of local row (mt*32 + lm)
    auto LDXF = [&](int mt, int ks) -> short8 {
        const int r = mt * 32 + lm;
        const unsigned byteoff = ((unsigned)(r * 256 + ks * 32 + h * 16)) ^ SWZ(r);
        return *(const short8*)(xh + byteoff);
    };
    // weight fragment: contiguous 1KB per wave instruction, per-wave slice w
    const unsigned short* Wl = Wshuf + (size_t)lane * 8;
    auto WF = [&](int g, int ks) -> short8 {
        return *(const short8*)(const void*)(Wl + (size_t)((g * 4 + w) * 8 + ks) * 512);
    };

    // ---- pass I: i-gate -> ik = sigm(i + bi) (f16 pairs) -------------------
    // acc C-layout: col = lane&31 (=m-local), n-local = (r&3)+8*(r>>2)+4*h
    unsigned ik[32];
    {
        short8 WiF[8];
        #pragma unroll
        for (int ks = 0; ks < 8; ++ks) WiF[ks] = WF(0, ks);
        #pragma unroll
        for (int mt = 0; mt < 4; ++mt) {
            f32x16 acc;
            #pragma unroll
            for (int e = 0; e < 16; ++e) acc[e] = 0.f;
            #pragma unroll
            for (int ks = 0; ks < 8; ++ks)
                acc = mfma_bf16(WiF[ks], LDXF(mt, ks), acc);
            #pragma unroll
            for (int q = 0; q < 4; ++q) {
                const int n0 = w * 32 + q * 8 + h * 4;
                const float4 bi = *(const float4*)(prm + 0 * 128 + n0);
                ik[mt*8+q*2+0] = pk_f16(sigm(acc[q*4+0] + bi.x), sigm(acc[q*4+1] + bi.y));
                ik[mt*8+q*2+1] = pk_f16(sigm(acc[q*4+2] + bi.z), sigm(acc[q*4+3] + bi.w));
            }
        }
    }

    // ---- pass S: s-gate -> ppk = ik * (s + bs) (f16 pairs) -----------------
    unsigned ppk[32];
    {
        short8 WsF[8];
        #pragma unroll
        for (int ks = 0; ks < 8; ++ks) WsF[ks] = WF(2, ks);
        #pragma unroll
        for (int mt = 0; mt < 4; ++mt) {
            f32x16 acc;
            #pragma unroll
            for (int e = 0; e < 16; ++e) acc[e] = 0.f;
            #pragma unroll
            for (int ks = 0; ks < 8; ++ks)
                acc = mfma_bf16(WsF[ks], LDXF(mt, ks), acc);
            #pragma unroll
            for (int q = 0; q < 4; ++q) {
                const int n0 = w * 32 + q * 8 + h * 4;
                const float4 bs = *(const float4*)(prm + 1 * 128 + n0);
                const unsigned ia = ik[mt*8+q*2+0], ib = ik[mt*8+q*2+1];
                ppk[mt*8+q*2+0] = pk_f16(lo_f16(ia) * (acc[q*4+0] + bs.x),
                                         hi_f16(ia) * (acc[q*4+1] + bs.y));
                ppk[mt*8+q*2+1] = pk_f16(lo_f16(ib) * (acc[q*4+2] + bs.z),
                                         hi_f16(ib) * (acc[q*4+3] + bs.w));
            }
        }
    }

    // ---- pass F: f-gate -> hpk = ppk + sigm(f + fb) * hp (bf16 pairs) ------
    unsigned hpk[32];
    {
        short8 WfF[8];
        #pragma unroll
        for (int ks = 0; ks < 8; ++ks) WfF[ks] = WF(1, ks);
        #pragma unroll
        for (int mt = 0; mt < 4; ++mt) {
            f32x16 acc;
            #pragma unroll
            for (int e = 0; e < 16; ++e) acc[e] = 0.f;
            #pragma unroll
            for (int ks = 0; ks < 8; ++ks)
                acc = mfma_bf16(WfF[ks], LDXF(mt, ks), acc);
            #pragma unroll
            for (int q = 0; q < 4; ++q) {
                const int n0 = w * 32 + q * 8 + h * 4;
                const float4 fb4 = *(const float4*)(prm + 2 * 128 + n0);
                const float4 hp4 = *(const float4*)(prm + 3 * 128 + n0);
                const unsigned pa = ppk[mt*8+q*2+0], pb = ppk[mt*8+q*2+1];
                const float h0 = lo_f16(pa) + sigm(acc[q*4+0] + fb4.x) * hp4.x;
                const float h1 = hi_f16(pa) + sigm(acc[q*4+1] + fb4.y) * hp4.y;
                const float h2 = lo_f16(pb) + sigm(acc[q*4+2] + fb4.z) * hp4.z;
                const float h3 = hi_f16(pb) + sigm(acc[q*4+3] + fb4.w) * hp4.w;
                hpk[mt*8+q*2+0] = pk_bf16(h0, h1);
                hpk[mt*8+q*2+1] = pk_bf16(h2, h3);
            }
        }
    }

    // ---- exchange h_raw through LDS (reuse x region) -----------------------
    __syncthreads();                      // everyone done reading x
    #pragma unroll
    for (int mt = 0; mt < 4; ++mt) {
        const int r = mt * 32 + lm;
        #pragma unroll
        for (int q = 0; q < 4; ++q) {
            const unsigned byteoff =
                ((unsigned)(r * 256 + (w * 32 + q * 8 + h * 4) * 2)) ^ SWZ(r);
            *(uint2*)(xh + byteoff) = make_uint2(hpk[mt*8+q*2+0], hpk[mt*8+q*2+1]);
        }
    }
    __syncthreads();                      // h_raw complete

    // ---- pass O (GEMM2): o = sigm(Wo @ h_raw + bo); h_out = o * tanh(h_raw)
    unsigned opk[32];
    float sums[4], ssqs[4];
    {
        short8 WoF[8];
        #pragma unroll
        for (int ks = 0; ks < 8; ++ks) WoF[ks] = WF(3, ks);
        #pragma unroll
        for (int mt = 0; mt < 4; ++mt) {
            f32x16 acc;
            #pragma unroll
            for (int e = 0; e < 16; ++e) acc[e] = 0.f;
            #pragma unroll
            for (int ks = 0; ks < 8; ++ks)
                acc = mfma_bf16(WoF[ks], LDXF(mt, ks), acc);   // xh now holds h_raw
            float sum = 0.f, ssq = 0.f;
            #pragma unroll
            for (int q = 0; q < 4; ++q) {
                const int n0 = w * 32 + q * 8 + h * 4;
                const float4 bo = *(const float4*)(prm + 4 * 128 + n0);
                const unsigned ha = hpk[mt*8+q*2+0], hb = hpk[mt*8+q*2+1];
                const float hv0 = sigm(acc[q*4+0] + bo.x) * tanh_fast(bf2f(ha & 0xffffu));
                const float hv1 = sigm(acc[q*4+1] + bo.y) * tanh_fast(bf2f(ha >> 16));
                const float hv2 = sigm(acc[q*4+2] + bo.z) * tanh_fast(bf2f(hb & 0xffffu));
                const float hv3 = sigm(acc[q*4+3] + bo.w) * tanh_fast(bf2f(hb >> 16));
                opk[mt*8+q*2+0] = pk_f16(hv0, hv1);
                opk[mt*8+q*2+1] = pk_f16(hv2, hv3);
                sum += hv0 + hv1 + hv2 + hv3;
                ssq += hv0*hv0 + hv1*hv1 + hv2*hv2 + hv3*hv3;
            }
            sum += __shfl_xor(sum, 32, 64);
            ssq += __shfl_xor(ssq, 32, 64);
            sums[mt] = sum; ssqs[mt] = ssq;
        }
    }

    // ---- cross-wave LN reduction ------------------------------------------
    if (h == 0) {
        #pragma unroll
        for (int mt = 0; mt < 4; ++mt) {
            red[w][mt][lm][0] = sums[mt];
            red[w][mt][lm][1] = ssqs[mt];
        }
    }
    __syncthreads();

    // ---- LN + store --------------------------------------------------------
    #pragma unroll
    for (int mt = 0; mt < 4; ++mt) {
        float s = 0.f, q2 = 0.f;
        #pragma unroll
        for (int ww = 0; ww < 4; ++ww) {
            s  += red[ww][mt][lm][0];
            q2 += red[ww][mt][lm][1];
        }
        const float mean = s * (1.0f / 128.0f);
        const float var  = q2 * (1.0f / 128.0f) - mean * mean;
        const float rstd = __builtin_amdgcn_rsqf(var + 1e-5f);
        float* orow = out + (row0 + (size_t)(mt * 32 + lm)) * 128;
        #pragma unroll
        for (int q = 0; q < 4; ++q) {
            const int n0 = w * 32 + q * 8 + h * 4;
            const float4 g4 = *(const float4*)(prm + 5 * 128 + n0);
            const float4 b4 = *(const float4*)(prm + 6 * 128 + n0);
            const unsigned oa = opk[mt*8+q*2+0], ob = opk[mt*8+q*2+1];
            float4 rr;
            rr.x = (lo_f16(oa) - mean) * rstd * g4.x + b4.x;
            rr.y = (hi_f16(oa) - mean) * rstd * g4.y + b4.y;
            rr.z = (lo_f16(ob) - mean) * rstd * g4.z + b4.z;
            rr.w = (hi_f16(ob) - mean) * rstd * g4.w + b4.w;
            *(float4*)(orow + n0) = rr;
        }
    }
}

// ------------------------------- launch ------------------------------------
extern "C" void kernel_launch(void* const* d_in, const int* in_sizes, int n_in,
                              void* d_out, int out_size, void* d_ws, size_t ws_size,
                              hipStream_t stream) {
    const float* x      = (const float*)d_in[0];
    const float* h_prev = (const float*)d_in[1];
    const float* Ws_w   = (const float*)d_in[2];
    const float* Ws_b   = (const float*)d_in[3];
    const float* Wfast  = (const float*)d_in[4];
    const float* Wi_w   = (const float*)d_in[5];
    const float* Wi_b   = (const float*)d_in[6];
    const float* Wf_w   = (const float*)d_in[7];
    const float* Wf_b   = (const float*)d_in[8];
    const float* Wo_w   = (const float*)d_in[9];
    const float* Wo_b   = (const float*)d_in[10];
    const float* ln_g   = (const float*)d_in[11];
    const float* ln_b   = (const float*)d_in[12];

    unsigned short* Wshuf = (unsigned short*)d_ws;           // 65536 bf16 = 128 KB
    float*          fb    = (float*)(Wshuf + 65536);         // 128 f32

    prep_weights<<<256, 256, 0, stream>>>(Wi_w, Wf_w, Ws_w, Wfast, Wo_w, Wshuf);
    prep_fbias<<<1, 128, 0, stream>>>(Wf_w, Wf_b, h_prev, fb);

    const int B = in_sizes[0] / 128;                         // 262144
    const int blocks = B / 128;                              // 128 rows per block
    cell_main<<<blocks, 256, 0, stream>>>(x, h_prev, Wi_b, Ws_b, Wo_b,
                                          ln_g, ln_b, Wshuf, fb,
                                          (float*)d_out);
}

// Round 6
// 711.485 us; speedup vs baseline: 1.0094x; 1.0094x over previous
//
#include <hip/hip_runtime.h>
#include <hip/hip_bf16.h>
#include <hip/hip_fp16.h>

// Fused AdvancedHomeostaticCell, round 6: n-sliced block, spill-proofed.
// R5 failed on SCRATCH SPILLS (2.9 GB phantom HBM traffic): 4 per-thread
// 32-dword arrays + reg-resident weights exceeded the register budget.
// R6: i+s gates fused into one pass (two accumulators) so at most two
// 32-dword arrays are live at once; one weight set (32 VGPR) per pass.
// Peak live ~140 regs < 170 (3 waves/SIMD).

typedef __attribute__((ext_vector_type(8)))  short short8;
typedef __attribute__((ext_vector_type(16))) float f32x16;

__device__ __forceinline__ unsigned short f2bf(float f) {   // prep kernels only
    union { float f; unsigned u; } v; v.f = f;
    unsigned r = v.u + 0x7fffu + ((v.u >> 16) & 1u);
    return (unsigned short)(r >> 16);
}
__device__ __forceinline__ float bf2f(unsigned hs) {
    union { unsigned u; float f; } v; v.u = hs << 16;
    return v.f;
}
__device__ __forceinline__ unsigned pk_bf16(float lo, float hi) {
    union { __hip_bfloat162 h; unsigned u; } c;
    c.h = __float22bfloat162_rn(make_float2(lo, hi));
    return c.u;
}
__device__ __forceinline__ unsigned pk_f16(float lo, float hi) {
    union { __half2 h; unsigned u; } c;
    c.h = __floats2half2_rn(lo, hi);
    return c.u;
}
__device__ __forceinline__ float lo_f16(unsigned u) {
    union { unsigned u; __half2 h; } c; c.u = u;
    return __low2float(c.h);
}
__device__ __forceinline__ float hi_f16(unsigned u) {
    union { unsigned u; __half2 h; } c; c.u = u;
    return __high2float(c.h);
}
__device__ __forceinline__ float rcp_fast(float x) { return __builtin_amdgcn_rcpf(x); }
__device__ __forceinline__ float exp2_fast(float x) { return __builtin_amdgcn_exp2f(x); }
__device__ __forceinline__ float sigm(float x) {
    return rcp_fast(1.0f + exp2_fast(-1.4426950408889634f * x));
}
__device__ __forceinline__ float tanh_fast(float x) {
    return 1.0f - 2.0f * rcp_fast(1.0f + exp2_fast(2.8853900817779268f * x));
}
__device__ __forceinline__ f32x16 mfma_bf16(short8 a, short8 b, f32x16 c) {
    return __builtin_amdgcn_mfma_f32_32x32x16_bf16(a, b, c, 0, 0, 0);
}

#define SWZ(r) ((unsigned)(((r) & 15) << 4))

// ---------- prep: fragment-major bf16 weights ------------------------------
// Wshuf element index = ((g*4 + jg)*8 + ks)*512 + lane*8 + e
//   g: 0=Wi, 1=Wf(x half), 2=Wslow+Wfast, 3=Wo ; jg: n-tile ; ks: k-tile
//   fragment value[e] = Wg[jg*32 + (lane&31)][ks*16 + (lane>>5)*8 + e]
__global__ void prep_weights(const float* __restrict__ Wi_w,
                             const float* __restrict__ Wf_w,
                             const float* __restrict__ Ws_w,
                             const float* __restrict__ Wfast_w,
                             const float* __restrict__ Wo_w,
                             unsigned short* __restrict__ Wshuf) {
    int gid = blockIdx.x * 256 + threadIdx.x;   // 0 .. 65535
    int e    = gid & 7;
    int lane = (gid >> 3) & 63;
    int ks   = (gid >> 9) & 7;
    int t    = gid >> 12;                       // g*4 + jg
    int g = t >> 2, jg = t & 3;
    int row = jg * 32 + (lane & 31);
    int k   = ks * 16 + (lane >> 5) * 8 + e;
    float v;
    if (g == 0)      v = Wi_w[row * 128 + k];
    else if (g == 1) v = Wf_w[row * 256 + k];
    else if (g == 2) v = Ws_w[row * 128 + k] + Wfast_w[row * 128 + k];
    else             v = Wo_w[row * 128 + k];
    Wshuf[gid] = f2bf(v);
}

// fbias[j] = Wf_b[j] + sum_k Wf_w[j][128+k] * h_prev[k]
__global__ void prep_fbias(const float* __restrict__ Wf_w,
                           const float* __restrict__ Wf_b,
                           const float* __restrict__ hp,
                           float* __restrict__ fbias) {
    int j = threadIdx.x;
    float s = Wf_b[j];
    for (int k = 0; k < 128; ++k) s += Wf_w[j * 256 + 128 + k] * hp[k];
    fbias[j] = s;
}

// ------------------------------ main fused kernel --------------------------
__global__ __launch_bounds__(256, 3)
void cell_main(const float* __restrict__ x,
               const float* __restrict__ hp,
               const float* __restrict__ Wi_b,
               const float* __restrict__ Ws_b,
               const float* __restrict__ Wo_b,
               const float* __restrict__ ln_g,
               const float* __restrict__ ln_b,
               const unsigned short* __restrict__ Wshuf,
               const float* __restrict__ fbias,
               float* __restrict__ out) {
    const int tid  = threadIdx.x;
    const int lane = tid & 63;
    const int w    = tid >> 6;          // wave id = n-slice index
    const int lm   = lane & 31;         // m-local (MFMA column) / weight row
    const int h    = lane >> 5;         // half-wave k-selector

    __shared__ __align__(16) char  xh[32768];          // x bf16 -> later h_raw
    __shared__ __align__(16) float prm[7 * 128];       // staged params
    __shared__ __align__(16) float red[4][4][32][2];   // [w][mt][lm][{sum,ssq}]

    const size_t row0 = (size_t)blockIdx.x * 128;

    // ---- phase A: stage x (bf16, swizzled rows of 256B) + params ----------
    {
        const float* xb = x + row0 * 128;
        #pragma unroll
        for (int it = 0; it < 16; ++it) {
            const int idx = it * 256 + tid;            // float4 index, coalesced
            const float4 v = *(const float4*)(xb + (size_t)idx * 4);
            const int r = idx >> 5;                    // local row
            const unsigned byteoff = ((unsigned)(r * 256 + (idx & 31) * 8)) ^ SWZ(r);
            *(uint2*)(xh + byteoff) = make_uint2(pk_bf16(v.x, v.y), pk_bf16(v.z, v.w));
        }
        if (tid < 224) {                               // 7 param arrays x 128 f32
            const int a = tid >> 5, e4 = (tid & 31) * 4;
            float4 v;
            switch (a) {
                case 0: v = *(const float4*)(Wi_b + e4); break;
                case 1: v = *(const float4*)(Ws_b + e4); break;
                case 2: v = *(const float4*)(fbias + e4); break;
                case 3: v = *(const float4*)(hp + e4); break;
                case 4: v = *(const float4*)(Wo_b + e4); break;
                case 5: v = *(const float4*)(ln_g + e4); break;
                default: v = *(const float4*)(ln_b + e4); break;
            }
            *(float4*)(prm + a * 128 + e4) = v;
        }
    }
    __syncthreads();

    // fragment read: k = ks*16 + h*8 + 0..7 of local row (mt*32 + lm)
    auto LDXF = [&](int mt, int ks) -> short8 {
        const int r = mt * 32 + lm;
        const unsigned byteoff = ((unsigned)(r * 256 + ks * 32 + h * 16)) ^ SWZ(r);
        return *(const short8*)(xh + byteoff);
    };
    // weight fragment: contiguous 1KB per wave instruction, per-wave slice w
    const unsigned short* Wl = Wshuf + (size_t)lane * 8;
    auto WF = [&](int g, int ks) -> short8 {
        return *(const short8*)(const void*)(Wl + (size_t)((g * 4 + w) * 8 + ks) * 512);
    };

    // ---- pass IS: i & s gates in one sweep -> ppk = sigm(i+bi)*(s+bs) ------
    // acc C-layout: col = lane&31 (=m-local), n-local = (r&3)+8*(r>>2)+4*h
    unsigned ppk[32];                    // f16 pairs
    {
        short8 WiF[8], WsF[8];
        #pragma unroll
        for (int ks = 0; ks < 8; ++ks) { WiF[ks] = WF(0, ks); WsF[ks] = WF(2, ks); }
        #pragma unroll
        for (int mt = 0; mt < 4; ++mt) {
            f32x16 ai, as;
            #pragma unroll
            for (int e = 0; e < 16; ++e) { ai[e] = 0.f; as[e] = 0.f; }
            #pragma unroll
            for (int ks = 0; ks < 8; ++ks) {
                const short8 xfv = LDXF(mt, ks);
                ai = mfma_bf16(WiF[ks], xfv, ai);
                as = mfma_bf16(WsF[ks], xfv, as);
            }
            #pragma unroll
            for (int q = 0; q < 4; ++q) {
                const int n0 = w * 32 + q * 8 + h * 4;
                const float4 bi = *(const float4*)(prm + 0 * 128 + n0);
                const float4 bs = *(const float4*)(prm + 1 * 128 + n0);
                ppk[mt*8+q*2+0] = pk_f16(sigm(ai[q*4+0] + bi.x) * (as[q*4+0] + bs.x),
                                         sigm(ai[q*4+1] + bi.y) * (as[q*4+1] + bs.y));
                ppk[mt*8+q*2+1] = pk_f16(sigm(ai[q*4+2] + bi.z) * (as[q*4+2] + bs.z),
                                         sigm(ai[q*4+3] + bi.w) * (as[q*4+3] + bs.w));
            }
        }
    }

    // ---- pass F: f-gate -> hpk = ppk + sigm(f + fb) * hp (bf16 pairs) ------
    unsigned hpk[32];
    {
        short8 WfF[8];
        #pragma unroll
        for (int ks = 0; ks < 8; ++ks) WfF[ks] = WF(1, ks);
        #pragma unroll
        for (int mt = 0; mt < 4; ++mt) {
            f32x16 acc;
            #pragma unroll
            for (int e = 0; e < 16; ++e) acc[e] = 0.f;
            #pragma unroll
            for (int ks = 0; ks < 8; ++ks)
                acc = mfma_bf16(WfF[ks], LDXF(mt, ks), acc);
            #pragma unroll
            for (int q = 0; q < 4; ++q) {
                const int n0 = w * 32 + q * 8 + h * 4;
                const float4 fb4 = *(const float4*)(prm + 2 * 128 + n0);
                const float4 hp4 = *(const float4*)(prm + 3 * 128 + n0);
                const unsigned pa = ppk[mt*8+q*2+0], pb = ppk[mt*8+q*2+1];
                const float h0 = lo_f16(pa) + sigm(acc[q*4+0] + fb4.x) * hp4.x;
                const float h1 = hi_f16(pa) + sigm(acc[q*4+1] + fb4.y) * hp4.y;
                const float h2 = lo_f16(pb) + sigm(acc[q*4+2] + fb4.z) * hp4.z;
                const float h3 = hi_f16(pb) + sigm(acc[q*4+3] + fb4.w) * hp4.w;
                hpk[mt*8+q*2+0] = pk_bf16(h0, h1);
                hpk[mt*8+q*2+1] = pk_bf16(h2, h3);
            }
        }
    }

    // ---- exchange h_raw through LDS (reuse x region) -----------------------
    __syncthreads();                      // everyone done reading x
    #pragma unroll
    for (int mt = 0; mt < 4; ++mt) {
        const int r = mt * 32 + lm;
        #pragma unroll
        for (int q = 0; q < 4; ++q) {
            const unsigned byteoff =
                ((unsigned)(r * 256 + (w * 32 + q * 8 + h * 4) * 2)) ^ SWZ(r);
            *(uint2*)(xh + byteoff) = make_uint2(hpk[mt*8+q*2+0], hpk[mt*8+q*2+1]);
        }
    }
    __syncthreads();                      // h_raw complete

    // ---- pass O (GEMM2): o = sigm(Wo @ h_raw + bo); h_out = o * tanh(h_raw)
    unsigned opk[32];
    float sums[4], ssqs[4];
    {
        short8 WoF[8];
        #pragma unroll
        for (int ks = 0; ks < 8; ++ks) WoF[ks] = WF(3, ks);
        #pragma unroll
        for (int mt = 0; mt < 4; ++mt) {
            f32x16 acc;
            #pragma unroll
            for (int e = 0; e < 16; ++e) acc[e] = 0.f;
            #pragma unroll
            for (int ks = 0; ks < 8; ++ks)
                acc = mfma_bf16(WoF[ks], LDXF(mt, ks), acc);   // xh now holds h_raw
            float sum = 0.f, ssq = 0.f;
            #pragma unroll
            for (int q = 0; q < 4; ++q) {
                const int n0 = w * 32 + q * 8 + h * 4;
                const float4 bo = *(const float4*)(prm + 4 * 128 + n0);
                const unsigned ha = hpk[mt*8+q*2+0], hb = hpk[mt*8+q*2+1];
                const float hv0 = sigm(acc[q*4+0] + bo.x) * tanh_fast(bf2f(ha & 0xffffu));
                const float hv1 = sigm(acc[q*4+1] + bo.y) * tanh_fast(bf2f(ha >> 16));
                const float hv2 = sigm(acc[q*4+2] + bo.z) * tanh_fast(bf2f(hb & 0xffffu));
                const float hv3 = sigm(acc[q*4+3] + bo.w) * tanh_fast(bf2f(hb >> 16));
                opk[mt*8+q*2+0] = pk_f16(hv0, hv1);
                opk[mt*8+q*2+1] = pk_f16(hv2, hv3);
                sum += hv0 + hv1 + hv2 + hv3;
                ssq += hv0*hv0 + hv1*hv1 + hv2*hv2 + hv3*hv3;
            }
            sum += __shfl_xor(sum, 32, 64);
            ssq += __shfl_xor(ssq, 32, 64);
            sums[mt] = sum; ssqs[mt] = ssq;
        }
    }

    // ---- cross-wave LN reduction ------------------------------------------
    if (h == 0) {
        #pragma unroll
        for (int mt = 0; mt < 4; ++mt) {
            red[w][mt][lm][0] = sums[mt];
            red[w][mt][lm][1] = ssqs[mt];
        }
    }
    __syncthreads();

    // ---- LN + store --------------------------------------------------------
    #pragma unroll
    for (int mt = 0; mt < 4; ++mt) {
        float s = 0.f, q2 = 0.f;
        #pragma unroll
        for (int ww = 0; ww < 4; ++ww) {
            s  += red[ww][mt][lm][0];
            q2 += red[ww][mt][lm][1];
        }
        const float mean = s * (1.0f / 128.0f);
        const float var  = q2 * (1.0f / 128.0f) - mean * mean;
        const float rstd = __builtin_amdgcn_rsqf(var + 1e-5f);
        float* orow = out + (row0 + (size_t)(mt * 32 + lm)) * 128;
        #pragma unroll
        for (int q = 0; q < 4; ++q) {
            const int n0 = w * 32 + q * 8 + h * 4;
            const float4 g4 = *(const float4*)(prm + 5 * 128 + n0);
            const float4 b4 = *(const float4*)(prm + 6 * 128 + n0);
            const unsigned oa = opk[mt*8+q*2+0], ob = opk[mt*8+q*2+1];
            float4 rr;
            rr.x = (lo_f16(oa) - mean) * rstd * g4.x + b4.x;
            rr.y = (hi_f16(oa) - mean) * rstd * g4.y + b4.y;
            rr.z = (lo_f16(ob) - mean) * rstd * g4.z + b4.z;
            rr.w = (hi_f16(ob) - mean) * rstd * g4.w + b4.w;
            *(float4*)(orow + n0) = rr;
        }
    }
}

// ------------------------------- launch ------------------------------------
extern "C" void kernel_launch(void* const* d_in, const int* in_sizes, int n_in,
                              void* d_out, int out_size, void* d_ws, size_t ws_size,
                              hipStream_t stream) {
    const float* x      = (const float*)d_in[0];
    const float* h_prev = (const float*)d_in[1];
    const float* Ws_w   = (const float*)d_in[2];
    const float* Ws_b   = (const float*)d_in[3];
    const float* Wfast  = (const float*)d_in[4];
    const float* Wi_w   = (const float*)d_in[5];
    const float* Wi_b   = (const float*)d_in[6];
    const float* Wf_w   = (const float*)d_in[7];
    const float* Wf_b   = (const float*)d_in[8];
    const float* Wo_w   = (const float*)d_in[9];
    const float* Wo_b   = (const float*)d_in[10];
    const float* ln_g   = (const float*)d_in[11];
    const float* ln_b   = (const float*)d_in[12];

    unsigned short* Wshuf = (unsigned short*)d_ws;           // 65536 bf16 = 128 KB
    float*          fb    = (float*)(Wshuf + 65536);         // 128 f32

    prep_weights<<<256, 256, 0, stream>>>(Wi_w, Wf_w, Ws_w, Wfast, Wo_w, Wshuf);
    prep_fbias<<<1, 128, 0, stream>>>(Wf_w, Wf_b, h_prev, fb);

    const int B = in_sizes[0] / 128;                         // 262144
    const int blocks = B / 128;                              // 128 rows per block
    cell_main<<<blocks, 256, 0, stream>>>(x, h_prev, Wi_b, Ws_b, Wo_b,
                                          ln_g, ln_b, Wshuf, fb,
                                          (float*)d_out);
}

// Round 7
// 102.459 us; speedup vs baseline: 7.0097x; 6.9441x over previous
//
#include <hip/hip_runtime.h>
#include <hip/hip_bf16.h>
#include <hip/hip_fp16.h>

// Fused AdvancedHomeostaticCell, round 7.
// R5/R6 failed on register spills (2.9 GB scratch traffic). R7 removes the
// pressure structurally: 64-row blocks (arrays halve to 16 dwords), weights
// staged per-gate into LDS from a pre-swizzled global image (never resident
// in registers), launch_bounds(256,2) so the allocator can't spill.
// Compute phase: all operands from LDS, zero global loads.

typedef __attribute__((ext_vector_type(8)))  short short8;
typedef __attribute__((ext_vector_type(16))) float f32x16;

__device__ __forceinline__ unsigned short f2bf(float f) {   // prep kernels only
    union { float f; unsigned u; } v; v.f = f;
    unsigned r = v.u + 0x7fffu + ((v.u >> 16) & 1u);
    return (unsigned short)(r >> 16);
}
__device__ __forceinline__ float bf2f(unsigned hs) {
    union { unsigned u; float f; } v; v.u = hs << 16;
    return v.f;
}
__device__ __forceinline__ unsigned pk_bf16(float lo, float hi) {
    union { __hip_bfloat162 h; unsigned u; } c;
    c.h = __float22bfloat162_rn(make_float2(lo, hi));
    return c.u;
}
__device__ __forceinline__ unsigned pk_f16(float lo, float hi) {
    union { __half2 h; unsigned u; } c;
    c.h = __floats2half2_rn(lo, hi);
    return c.u;
}
__device__ __forceinline__ float lo_f16(unsigned u) {
    union { unsigned u; __half2 h; } c; c.u = u;
    return __low2float(c.h);
}
__device__ __forceinline__ float hi_f16(unsigned u) {
    union { unsigned u; __half2 h; } c; c.u = u;
    return __high2float(c.h);
}
__device__ __forceinline__ float rcp_fast(float x) { return __builtin_amdgcn_rcpf(x); }
__device__ __forceinline__ float exp2_fast(float x) { return __builtin_amdgcn_exp2f(x); }
__device__ __forceinline__ float sigm(float x) {
    return rcp_fast(1.0f + exp2_fast(-1.4426950408889634f * x));
}
__device__ __forceinline__ float tanh_fast(float x) {
    return 1.0f - 2.0f * rcp_fast(1.0f + exp2_fast(2.8853900817779268f * x));
}
__device__ __forceinline__ f32x16 mfma_bf16(short8 a, short8 b, f32x16 c) {
    return __builtin_amdgcn_mfma_f32_32x32x16_bf16(a, b, c, 0, 0, 0);
}

#define SWZ(r) ((unsigned)(((r) & 15) << 4))

// ---------- prep: per-gate pre-swizzled 32KB LDS weight images -------------
// Gate order g: 0=Wi, 1=Wslow+Wfast, 2=Wf(x half), 3=Wo.
// Image byte layout: row r (0..127) occupies [r*256, r*256+256); the data for
// unswizzled in-row byte b is stored at b ^ SWZ(r). Blocks copy the image
// LINEARLY into LDS; compute reads with the same XOR -> conflict-free.
__global__ void prep_wimg(const float* __restrict__ Wi_w,
                          const float* __restrict__ Wf_w,
                          const float* __restrict__ Ws_w,
                          const float* __restrict__ Wfast_w,
                          const float* __restrict__ Wo_w,
                          unsigned short* __restrict__ Wimg) {
    int gid = blockIdx.x * 256 + threadIdx.x;   // 0..65535 bf16 elements
    int g = gid >> 14;                          // 16384 per gate
    int e = gid & 16383;
    int r = e >> 7;                             // row 0..127
    int k = (((e & 127) * 2) ^ SWZ(r)) >> 1;    // source column
    float v;
    if (g == 0)      v = Wi_w[r * 128 + k];
    else if (g == 1) v = Ws_w[r * 128 + k] + Wfast_w[r * 128 + k];
    else if (g == 2) v = Wf_w[r * 256 + k];
    else             v = Wo_w[r * 128 + k];
    Wimg[gid] = f2bf(v);
}

// fbias[j] = Wf_b[j] + sum_k Wf_w[j][128+k] * h_prev[k]
__global__ void prep_fbias(const float* __restrict__ Wf_w,
                           const float* __restrict__ Wf_b,
                           const float* __restrict__ hp,
                           float* __restrict__ fbias) {
    int j = threadIdx.x;
    float s = Wf_b[j];
    for (int k = 0; k < 128; ++k) s += Wf_w[j * 256 + 128 + k] * hp[k];
    fbias[j] = s;
}

// ------------------------------ main fused kernel --------------------------
__global__ __launch_bounds__(256, 2)
void cell_main(const float* __restrict__ x,
               const float* __restrict__ hp,
               const float* __restrict__ Wi_b,
               const float* __restrict__ Ws_b,
               const float* __restrict__ Wo_b,
               const float* __restrict__ ln_g,
               const float* __restrict__ ln_b,
               const unsigned short* __restrict__ Wimg,
               const float* __restrict__ fbias,
               float* __restrict__ out) {
    const int tid  = threadIdx.x;
    const int lane = tid & 63;
    const int w    = tid >> 6;          // wave id = n-slice [32w, 32w+32)
    const int lm   = lane & 31;         // m-local (MFMA column) / weight row
    const int h    = lane >> 5;         // half-wave k-selector

    __shared__ __align__(16) char  xh[16384];    // 64 rows x 256B: x -> h_raw
    __shared__ __align__(16) char  wb[32768];    // current gate weights
    __shared__ __align__(16) float prm[7 * 128]; // staged params

    const size_t row0 = (size_t)blockIdx.x * 64;

    auto stageW = [&](int g) {                   // linear 32KB copy, coalesced
        const uint4* src = (const uint4*)(Wimg + (size_t)g * 16384);
        #pragma unroll
        for (int j = 0; j < 8; ++j)
            ((uint4*)wb)[j * 256 + tid] = src[j * 256 + tid];
    };
    auto WFRD = [&](int ks) -> short8 {          // weight frag, row w*32+lm
        const int r = w * 32 + lm;
        const unsigned off = (unsigned)(r * 256) + (((unsigned)(ks * 32 + h * 16)) ^ SWZ(r));
        return *(const short8*)(wb + off);
    };
    auto LDXF = [&](int mt, int ks) -> short8 {  // x / h_raw frag, row mt*32+lm
        const int r = mt * 32 + lm;
        const unsigned off = (unsigned)(r * 256) + (((unsigned)(ks * 32 + h * 16)) ^ SWZ(r));
        return *(const short8*)(xh + off);
    };

    // ---- stage x (coalesced f32 -> bf16 swizzled), params, Wi --------------
    {
        const float4* xb = (const float4*)(x + row0 * 128);  // 2048 float4
        #pragma unroll
        for (int it = 0; it < 8; ++it) {
            const int idx = it * 256 + tid;
            const float4 v = xb[idx];
            const int r = idx >> 5;
            const unsigned off = ((unsigned)(r * 256 + (idx & 31) * 8)) ^ SWZ(r);
            *(uint2*)(xh + off) = make_uint2(pk_bf16(v.x, v.y), pk_bf16(v.z, v.w));
        }
        if (tid < 224) {                          // 7 param arrays x 128 f32
            const int a = tid >> 5, e4 = (tid & 31) * 4;
            float4 v;
            switch (a) {
                case 0: v = *(const float4*)(Wi_b + e4); break;
                case 1: v = *(const float4*)(Ws_b + e4); break;
                case 2: v = *(const float4*)(fbias + e4); break;
                case 3: v = *(const float4*)(hp + e4); break;
                case 4: v = *(const float4*)(Wo_b + e4); break;
                case 5: v = *(const float4*)(ln_g + e4); break;
                default: v = *(const float4*)(ln_b + e4); break;
            }
            *(float4*)(prm + a * 128 + e4) = v;
        }
        stageW(0);
    }
    __syncthreads();

    // ---- pass I: ik = sigm(Wi@x + bi) (f16 pairs) --------------------------
    // acc C-layout: col = lm (=m-local), n-local = j + 8q + 4h
    unsigned ik[16];
    {
        short8 WF[8];
        #pragma unroll
        for (int ks = 0; ks < 8; ++ks) WF[ks] = WFRD(ks);
        #pragma unroll
        for (int mt = 0; mt < 2; ++mt) {
            f32x16 acc;
            #pragma unroll
            for (int e = 0; e < 16; ++e) acc[e] = 0.f;
            #pragma unroll
            for (int ks = 0; ks < 8; ++ks)
                acc = mfma_bf16(WF[ks], LDXF(mt, ks), acc);
            #pragma unroll
            for (int q = 0; q < 4; ++q) {
                const int n0 = w * 32 + q * 8 + h * 4;
                const float4 bi = *(const float4*)(prm + 0 * 128 + n0);
                ik[mt*8+q*2+0] = pk_f16(sigm(acc[q*4+0] + bi.x), sigm(acc[q*4+1] + bi.y));
                ik[mt*8+q*2+1] = pk_f16(sigm(acc[q*4+2] + bi.z), sigm(acc[q*4+3] + bi.w));
            }
        }
    }
    __syncthreads();
    stageW(1);
    __syncthreads();

    // ---- pass S: ppk = ik * (Ws@x + bs) (f16 pairs) ------------------------
    unsigned ppk[16];
    {
        short8 WF[8];
        #pragma unroll
        for (int ks = 0; ks < 8; ++ks) WF[ks] = WFRD(ks);
        #pragma unroll
        for (int mt = 0; mt < 2; ++mt) {
            f32x16 acc;
            #pragma unroll
            for (int e = 0; e < 16; ++e) acc[e] = 0.f;
            #pragma unroll
            for (int ks = 0; ks < 8; ++ks)
                acc = mfma_bf16(WF[ks], LDXF(mt, ks), acc);
            #pragma unroll
            for (int q = 0; q < 4; ++q) {
                const int n0 = w * 32 + q * 8 + h * 4;
                const float4 bs = *(const float4*)(prm + 1 * 128 + n0);
                const unsigned ia = ik[mt*8+q*2+0], ib = ik[mt*8+q*2+1];
                ppk[mt*8+q*2+0] = pk_f16(lo_f16(ia) * (acc[q*4+0] + bs.x),
                                         hi_f16(ia) * (acc[q*4+1] + bs.y));
                ppk[mt*8+q*2+1] = pk_f16(lo_f16(ib) * (acc[q*4+2] + bs.z),
                                         hi_f16(ib) * (acc[q*4+3] + bs.w));
            }
        }
    }
    __syncthreads();
    stageW(2);
    __syncthreads();

    // ---- pass F: hpk = ppk + sigm(Wf@x + fb) * hp (bf16 pairs) -------------
    unsigned hpk[16];
    {
        short8 WF[8];
        #pragma unroll
        for (int ks = 0; ks < 8; ++ks) WF[ks] = WFRD(ks);
        #pragma unroll
        for (int mt = 0; mt < 2; ++mt) {
            f32x16 acc;
            #pragma unroll
            for (int e = 0; e < 16; ++e) acc[e] = 0.f;
            #pragma unroll
            for (int ks = 0; ks < 8; ++ks)
                acc = mfma_bf16(WF[ks], LDXF(mt, ks), acc);
            #pragma unroll
            for (int q = 0; q < 4; ++q) {
                const int n0 = w * 32 + q * 8 + h * 4;
                const float4 fb4 = *(const float4*)(prm + 2 * 128 + n0);
                const float4 hp4 = *(const float4*)(prm + 3 * 128 + n0);
                const unsigned pa = ppk[mt*8+q*2+0], pb = ppk[mt*8+q*2+1];
                hpk[mt*8+q*2+0] = pk_bf16(lo_f16(pa) + sigm(acc[q*4+0] + fb4.x) * hp4.x,
                                          hi_f16(pa) + sigm(acc[q*4+1] + fb4.y) * hp4.y);
                hpk[mt*8+q*2+1] = pk_bf16(lo_f16(pb) + sigm(acc[q*4+2] + fb4.z) * hp4.z,
                                          hi_f16(pb) + sigm(acc[q*4+3] + fb4.w) * hp4.w);
            }
        }
    }
    __syncthreads();                 // all x reads + Wf reads done

    // ---- h_raw -> xh (swizzled) and stage Wo -------------------------------
    #pragma unroll
    for (int mt = 0; mt < 2; ++mt) {
        const int r = mt * 32 + lm;
        #pragma unroll
        for (int q = 0; q < 4; ++q) {
            const unsigned off = (unsigned)(r * 256)
                + (((unsigned)((w * 32 + q * 8 + h * 4) * 2)) ^ SWZ(r));
            *(uint2*)(xh + off) = make_uint2(hpk[mt*8+q*2+0], hpk[mt*8+q*2+1]);
        }
    }
    stageW(3);
    __syncthreads();                 // h_raw visible + Wo staged

    // ---- pass O: o = sigm(Wo@h_raw + bo); h_out = o*tanh(h_raw) ------------
    unsigned opk[16];
    float sums[2], ssqs[2];
    {
        short8 WF[8];
        #pragma unroll
        for (int ks = 0; ks < 8; ++ks) WF[ks] = WFRD(ks);
        #pragma unroll
        for (int mt = 0; mt < 2; ++mt) {
            f32x16 acc;
            #pragma unroll
            for (int e = 0; e < 16; ++e) acc[e] = 0.f;
            #pragma unroll
            for (int ks = 0; ks < 8; ++ks)
                acc = mfma_bf16(WF[ks], LDXF(mt, ks), acc);   // xh = h_raw now
            float sum = 0.f, ssq = 0.f;
            #pragma unroll
            for (int q = 0; q < 4; ++q) {
                const int n0 = w * 32 + q * 8 + h * 4;
                const float4 bo = *(const float4*)(prm + 4 * 128 + n0);
                const unsigned ha = hpk[mt*8+q*2+0], hb = hpk[mt*8+q*2+1];
                const float hv0 = sigm(acc[q*4+0] + bo.x) * tanh_fast(bf2f(ha & 0xffffu));
                const float hv1 = sigm(acc[q*4+1] + bo.y) * tanh_fast(bf2f(ha >> 16));
                const float hv2 = sigm(acc[q*4+2] + bo.z) * tanh_fast(bf2f(hb & 0xffffu));
                const float hv3 = sigm(acc[q*4+3] + bo.w) * tanh_fast(bf2f(hb >> 16));
                opk[mt*8+q*2+0] = pk_f16(hv0, hv1);
                opk[mt*8+q*2+1] = pk_f16(hv2, hv3);
                sum += hv0 + hv1 + hv2 + hv3;
                ssq += hv0*hv0 + hv1*hv1 + hv2*hv2 + hv3*hv3;
            }
            sum += __shfl_xor(sum, 32, 64);
            ssq += __shfl_xor(ssq, 32, 64);
            sums[mt] = sum; ssqs[mt] = ssq;
        }
    }
    __syncthreads();                 // Wo reads done -> wb reusable as red

    // ---- cross-wave LN reduction (red aliases wb) --------------------------
    float* red = (float*)wb;         // [mt][w][lm][{sum,ssq}] = 512 floats
    if (h == 0) {
        #pragma unroll
        for (int mt = 0; mt < 2; ++mt) {
            red[((mt * 4 + w) * 32 + lm) * 2 + 0] = sums[mt];
            red[((mt * 4 + w) * 32 + lm) * 2 + 1] = ssqs[mt];
        }
    }
    __syncthreads();

    // ---- LN + store --------------------------------------------------------
    #pragma unroll
    for (int mt = 0; mt < 2; ++mt) {
        float s = 0.f, q2 = 0.f;
        #pragma unroll
        for (int ww = 0; ww < 4; ++ww) {
            s  += red[((mt * 4 + ww) * 32 + lm) * 2 + 0];
            q2 += red[((mt * 4 + ww) * 32 + lm) * 2 + 1];
        }
        const float mean = s * (1.0f / 128.0f);
        const float var  = q2 * (1.0f / 128.0f) - mean * mean;
        const float rstd = __builtin_amdgcn_rsqf(var + 1e-5f);
        float* orow = out + (row0 + (size_t)(mt * 32 + lm)) * 128;
        #pragma unroll
        for (int q = 0; q < 4; ++q) {
            const int n0 = w * 32 + q * 8 + h * 4;
            const float4 g4 = *(const float4*)(prm + 5 * 128 + n0);
            const float4 b4 = *(const float4*)(prm + 6 * 128 + n0);
            const unsigned oa = opk[mt*8+q*2+0], ob = opk[mt*8+q*2+1];
            float4 rr;
            rr.x = (lo_f16(oa) - mean) * rstd * g4.x + b4.x;
            rr.y = (hi_f16(oa) - mean) * rstd * g4.y + b4.y;
            rr.z = (lo_f16(ob) - mean) * rstd * g4.z + b4.z;
            rr.w = (hi_f16(ob) - mean) * rstd * g4.w + b4.w;
            *(float4*)(orow + n0) = rr;
        }
    }
}

// ------------------------------- launch ------------------------------------
extern "C" void kernel_launch(void* const* d_in, const int* in_sizes, int n_in,
                              void* d_out, int out_size, void* d_ws, size_t ws_size,
                              hipStream_t stream) {
    const float* x      = (const float*)d_in[0];
    const float* h_prev = (const float*)d_in[1];
    const float* Ws_w   = (const float*)d_in[2];
    const float* Ws_b   = (const float*)d_in[3];
    const float* Wfast  = (const float*)d_in[4];
    const float* Wi_w   = (const float*)d_in[5];
    const float* Wi_b   = (const float*)d_in[6];
    const float* Wf_w   = (const float*)d_in[7];
    const float* Wf_b   = (const float*)d_in[8];
    const float* Wo_w   = (const float*)d_in[9];
    const float* Wo_b   = (const float*)d_in[10];
    const float* ln_g   = (const float*)d_in[11];
    const float* ln_b   = (const float*)d_in[12];

    unsigned short* Wimg = (unsigned short*)d_ws;            // 4 x 16384 bf16 = 128 KB
    float*          fb   = (float*)(Wimg + 65536);           // 128 f32

    prep_wimg<<<256, 256, 0, stream>>>(Wi_w, Wf_w, Ws_w, Wfast, Wo_w, Wimg);
    prep_fbias<<<1, 128, 0, stream>>>(Wf_w, Wf_b, h_prev, fb);

    const int B = in_sizes[0] / 128;                         // 262144
    const int blocks = B / 64;                               // 64 rows per block
    cell_main<<<blocks, 256, 0, stream>>>(x, h_prev, Wi_b, Ws_b, Wo_b,
                                          ln_g, ln_b, Wimg, fb,
                                          (float*)d_out);
}

// Round 8
// 92.472 us; speedup vs baseline: 7.7667x; 1.1080x over previous
//
#include <hip/hip_runtime.h>
#include <hip/hip_bf16.h>
#include <hip/hip_fp16.h>

// Fused AdvancedHomeostaticCell, round 8.
// vs R7: weight-LDS staging removed (per-wave direct fragment-major global
// loads, L2-resident, 1KB/wave each); no barriers between gate passes;
// LDS ~24KB -> ~2x occupancy; coalesced output via LDS transpose.

typedef __attribute__((ext_vector_type(8)))  short short8;
typedef __attribute__((ext_vector_type(16))) float f32x16;

__device__ __forceinline__ unsigned short f2bf(float f) {   // prep kernels only
    union { float f; unsigned u; } v; v.f = f;
    unsigned r = v.u + 0x7fffu + ((v.u >> 16) & 1u);
    return (unsigned short)(r >> 16);
}
__device__ __forceinline__ unsigned pk_bf16(float lo, float hi) {
    union { __hip_bfloat162 h; unsigned u; } c;
    c.h = __float22bfloat162_rn(make_float2(lo, hi));
    return c.u;
}
__device__ __forceinline__ unsigned pk_f16(float lo, float hi) {
    union { __half2 h; unsigned u; } c;
    c.h = __floats2half2_rn(lo, hi);
    return c.u;
}
__device__ __forceinline__ float lo_f16(unsigned u) {
    union { unsigned u; __half2 h; } c; c.u = u;
    return __low2float(c.h);
}
__device__ __forceinline__ float hi_f16(unsigned u) {
    union { unsigned u; __half2 h; } c; c.u = u;
    return __high2float(c.h);
}
__device__ __forceinline__ float bf2f(unsigned hs) {
    union { unsigned u; float f; } v; v.u = hs << 16;
    return v.f;
}
__device__ __forceinline__ float rcp_fast(float x) { return __builtin_amdgcn_rcpf(x); }
__device__ __forceinline__ float exp2_fast(float x) { return __builtin_amdgcn_exp2f(x); }
__device__ __forceinline__ float sigm(float x) {
    return rcp_fast(1.0f + exp2_fast(-1.4426950408889634f * x));
}
__device__ __forceinline__ float tanh_fast(float x) {
    return 1.0f - 2.0f * rcp_fast(1.0f + exp2_fast(2.8853900817779268f * x));
}
__device__ __forceinline__ f32x16 mfma_bf16(short8 a, short8 b, f32x16 c) {
    return __builtin_amdgcn_mfma_f32_32x32x16_bf16(a, b, c, 0, 0, 0);
}

#define SWZ(r) ((unsigned)(((r) & 15) << 4))

// ---------- prep: fragment-major bf16 weights (R4 layout) ------------------
// Wshuf element index = ((g*4 + jg)*8 + ks)*512 + lane*8 + e
//   g: 0=Wi, 1=Wf(x half), 2=Wslow+Wfast, 3=Wo ; jg: n-tile ; ks: k-tile
//   value[e] = Wg[jg*32 + (lane&31)][ks*16 + (lane>>5)*8 + e]
__global__ void prep_weights(const float* __restrict__ Wi_w,
                             const float* __restrict__ Wf_w,
                             const float* __restrict__ Ws_w,
                             const float* __restrict__ Wfast_w,
                             const float* __restrict__ Wo_w,
                             unsigned short* __restrict__ Wshuf) {
    int gid = blockIdx.x * 256 + threadIdx.x;   // 0 .. 65535
    int e    = gid & 7;
    int lane = (gid >> 3) & 63;
    int ks   = (gid >> 9) & 7;
    int t    = gid >> 12;                       // g*4 + jg
    int g = t >> 2, jg = t & 3;
    int row = jg * 32 + (lane & 31);
    int k   = ks * 16 + (lane >> 5) * 8 + e;
    float v;
    if (g == 0)      v = Wi_w[row * 128 + k];
    else if (g == 1) v = Wf_w[row * 256 + k];
    else if (g == 2) v = Ws_w[row * 128 + k] + Wfast_w[row * 128 + k];
    else             v = Wo_w[row * 128 + k];
    Wshuf[gid] = f2bf(v);
}

// fbias[j] = Wf_b[j] + sum_k Wf_w[j][128+k] * h_prev[k]
__global__ void prep_fbias(const float* __restrict__ Wf_w,
                           const float* __restrict__ Wf_b,
                           const float* __restrict__ hp,
                           float* __restrict__ fbias) {
    int j = threadIdx.x;
    float s = Wf_b[j];
    for (int k = 0; k < 128; ++k) s += Wf_w[j * 256 + 128 + k] * hp[k];
    fbias[j] = s;
}

// ------------------------------ main fused kernel --------------------------
__global__ __launch_bounds__(256, 2)
void cell_main(const float* __restrict__ x,
               const float* __restrict__ hp,
               const float* __restrict__ Wi_b,
               const float* __restrict__ Ws_b,
               const float* __restrict__ Wo_b,
               const float* __restrict__ ln_g,
               const float* __restrict__ ln_b,
               const unsigned short* __restrict__ Wshuf,
               const float* __restrict__ fbias,
               float* __restrict__ out) {
    const int tid  = threadIdx.x;
    const int lane = tid & 63;
    const int w    = tid >> 6;          // wave id = n-slice [32w, 32w+32)
    const int lm   = lane & 31;         // m-local (MFMA column) / weight row
    const int h    = lane >> 5;         // half-wave k-selector

    __shared__ __align__(16) char  xh[16384];      // 64 rows x 256B: x->h_raw->h_out
    __shared__ __align__(16) float prm[7 * 128];   // staged params
    __shared__ __align__(16) float red[4][4][32][2]; // [mt][w][lm][{sum,ssq}]
    __shared__ __align__(16) float red2[64][2];    // [row][{mean,rstd}]

    const size_t row0 = (size_t)blockIdx.x * 64;

    // ---- stage x (coalesced f32 -> bf16 swizzled) + params -----------------
    {
        const float4* xb = (const float4*)(x + row0 * 128);  // 2048 float4
        #pragma unroll
        for (int it = 0; it < 8; ++it) {
            const int idx = it * 256 + tid;
            const float4 v = xb[idx];
            const int r = idx >> 5;
            const unsigned off = ((unsigned)(r * 256 + (idx & 31) * 8)) ^ SWZ(r);
            *(uint2*)(xh + off) = make_uint2(pk_bf16(v.x, v.y), pk_bf16(v.z, v.w));
        }
        if (tid < 224) {                          // 7 param arrays x 128 f32
            const int a = tid >> 5, e4 = (tid & 31) * 4;
            float4 v;
            switch (a) {
                case 0: v = *(const float4*)(Wi_b + e4); break;
                case 1: v = *(const float4*)(Ws_b + e4); break;
                case 2: v = *(const float4*)(fbias + e4); break;
                case 3: v = *(const float4*)(hp + e4); break;
                case 4: v = *(const float4*)(Wo_b + e4); break;
                case 5: v = *(const float4*)(ln_g + e4); break;
                default: v = *(const float4*)(ln_b + e4); break;
            }
            *(float4*)(prm + a * 128 + e4) = v;
        }
    }
    __syncthreads();                              // B1

    auto LDXF = [&](int mt, int ks) -> short8 {   // x / h_raw frag, row mt*32+lm
        const int r = mt * 32 + lm;
        const unsigned off = (unsigned)(r * 256) + (((unsigned)(ks * 32 + h * 16)) ^ SWZ(r));
        return *(const short8*)(xh + off);
    };
    // direct fragment-major weight load: wave-contiguous 1KB from L2-resident image
    const unsigned short* Wl = Wshuf + (size_t)lane * 8;
    auto WFG = [&](int g, int ks) -> short8 {
        return *(const short8*)(const void*)(Wl + (size_t)((g * 4 + w) * 8 + ks) * 512);
    };

    // ---- pass I: ik = sigm(Wi@x + bi) (f16 pairs) --------------------------
    // acc C-layout: col = lm (=m-local), n-local = j + 8q + 4h
    unsigned ik[16];
    #pragma unroll
    for (int mt = 0; mt < 2; ++mt) {
        f32x16 acc;
        #pragma unroll
        for (int e = 0; e < 16; ++e) acc[e] = 0.f;
        #pragma unroll
        for (int ks = 0; ks < 8; ++ks)
            acc = mfma_bf16(WFG(0, ks), LDXF(mt, ks), acc);
        #pragma unroll
        for (int q = 0; q < 4; ++q) {
            const int n0 = w * 32 + q * 8 + h * 4;
            const float4 bi = *(const float4*)(prm + 0 * 128 + n0);
            ik[mt*8+q*2+0] = pk_f16(sigm(acc[q*4+0] + bi.x), sigm(acc[q*4+1] + bi.y));
            ik[mt*8+q*2+1] = pk_f16(sigm(acc[q*4+2] + bi.z), sigm(acc[q*4+3] + bi.w));
        }
    }

    // ---- pass S: ppk = ik * (Ws@x + bs) (f16 pairs) ------------------------
    unsigned ppk[16];
    #pragma unroll
    for (int mt = 0; mt < 2; ++mt) {
        f32x16 acc;
        #pragma unroll
        for (int e = 0; e < 16; ++e) acc[e] = 0.f;
        #pragma unroll
        for (int ks = 0; ks < 8; ++ks)
            acc = mfma_bf16(WFG(2, ks), LDXF(mt, ks), acc);
        #pragma unroll
        for (int q = 0; q < 4; ++q) {
            const int n0 = w * 32 + q * 8 + h * 4;
            const float4 bs = *(const float4*)(prm + 1 * 128 + n0);
            const unsigned ia = ik[mt*8+q*2+0], ib = ik[mt*8+q*2+1];
            ppk[mt*8+q*2+0] = pk_f16(lo_f16(ia) * (acc[q*4+0] + bs.x),
                                     hi_f16(ia) * (acc[q*4+1] + bs.y));
            ppk[mt*8+q*2+1] = pk_f16(lo_f16(ib) * (acc[q*4+2] + bs.z),
                                     hi_f16(ib) * (acc[q*4+3] + bs.w));
        }
    }

    // ---- pass F: hpk = ppk + sigm(Wf@x + fb) * hp (bf16 pairs) -------------
    unsigned hpk[16];
    #pragma unroll
    for (int mt = 0; mt < 2; ++mt) {
        f32x16 acc;
        #pragma unroll
        for (int e = 0; e < 16; ++e) acc[e] = 0.f;
        #pragma unroll
        for (int ks = 0; ks < 8; ++ks)
            acc = mfma_bf16(WFG(1, ks), LDXF(mt, ks), acc);
        #pragma unroll
        for (int q = 0; q < 4; ++q) {
            const int n0 = w * 32 + q * 8 + h * 4;
            const float4 fb4 = *(const float4*)(prm + 2 * 128 + n0);
            const float4 hp4 = *(const float4*)(prm + 3 * 128 + n0);
            const unsigned pa = ppk[mt*8+q*2+0], pb = ppk[mt*8+q*2+1];
            hpk[mt*8+q*2+0] = pk_bf16(lo_f16(pa) + sigm(acc[q*4+0] + fb4.x) * hp4.x,
                                      hi_f16(pa) + sigm(acc[q*4+1] + fb4.y) * hp4.y);
            hpk[mt*8+q*2+1] = pk_bf16(lo_f16(pb) + sigm(acc[q*4+2] + fb4.z) * hp4.z,
                                      hi_f16(pb) + sigm(acc[q*4+3] + fb4.w) * hp4.w);
        }
    }
    __syncthreads();                              // B2: all x reads done

    // ---- h_raw -> xh (swizzled) --------------------------------------------
    #pragma unroll
    for (int mt = 0; mt < 2; ++mt) {
        const int r = mt * 32 + lm;
        #pragma unroll
        for (int q = 0; q < 4; ++q) {
            const unsigned off = (unsigned)(r * 256)
                + (((unsigned)((w * 32 + q * 8 + h * 4) * 2)) ^ SWZ(r));
            *(uint2*)(xh + off) = make_uint2(hpk[mt*8+q*2+0], hpk[mt*8+q*2+1]);
        }
    }
    __syncthreads();                              // B3: h_raw visible

    // ---- pass O: o = sigm(Wo@h_raw + bo); h_out = o*tanh(h_raw) ------------
    unsigned opk[16];
    {
        float sums[2], ssqs[2];
        #pragma unroll
        for (int mt = 0; mt < 2; ++mt) {
            f32x16 acc;
            #pragma unroll
            for (int e = 0; e < 16; ++e) acc[e] = 0.f;
            #pragma unroll
            for (int ks = 0; ks < 8; ++ks)
                acc = mfma_bf16(WFG(3, ks), LDXF(mt, ks), acc);   // xh = h_raw
            float sum = 0.f, ssq = 0.f;
            #pragma unroll
            for (int q = 0; q < 4; ++q) {
                const int n0 = w * 32 + q * 8 + h * 4;
                const float4 bo = *(const float4*)(prm + 4 * 128 + n0);
                const unsigned ha = hpk[mt*8+q*2+0], hb = hpk[mt*8+q*2+1];
                const float hv0 = sigm(acc[q*4+0] + bo.x) * tanh_fast(bf2f(ha & 0xffffu));
                const float hv1 = sigm(acc[q*4+1] + bo.y) * tanh_fast(bf2f(ha >> 16));
                const float hv2 = sigm(acc[q*4+2] + bo.z) * tanh_fast(bf2f(hb & 0xffffu));
                const float hv3 = sigm(acc[q*4+3] + bo.w) * tanh_fast(bf2f(hb >> 16));
                opk[mt*8+q*2+0] = pk_f16(hv0, hv1);
                opk[mt*8+q*2+1] = pk_f16(hv2, hv3);
                sum += hv0 + hv1 + hv2 + hv3;
                ssq += hv0*hv0 + hv1*hv1 + hv2*hv2 + hv3*hv3;
            }
            sum += __shfl_xor(sum, 32, 64);
            ssq += __shfl_xor(ssq, 32, 64);
            sums[mt] = sum; ssqs[mt] = ssq;
        }
        if (h == 0) {
            #pragma unroll
            for (int mt = 0; mt < 2; ++mt) {
                red[mt][w][lm][0] = sums[mt];
                red[mt][w][lm][1] = ssqs[mt];
            }
        }
    }
    __syncthreads();                              // B4: h_raw reads + red done

    // ---- h_out -> xh (f16 pairs, swizzled); finalize row stats -------------
    #pragma unroll
    for (int mt = 0; mt < 2; ++mt) {
        const int r = mt * 32 + lm;
        #pragma unroll
        for (int q = 0; q < 4; ++q) {
            const unsigned off = (unsigned)(r * 256)
                + (((unsigned)((w * 32 + q * 8 + h * 4) * 2)) ^ SWZ(r));
            *(uint2*)(xh + off) = make_uint2(opk[mt*8+q*2+0], opk[mt*8+q*2+1]);
        }
    }
    if (tid < 64) {
        const int mt = tid >> 5, l = tid & 31;
        float s = 0.f, q2 = 0.f;
        #pragma unroll
        for (int ww = 0; ww < 4; ++ww) {
            s  += red[mt][ww][l][0];
            q2 += red[mt][ww][l][1];
        }
        const float mean = s * (1.0f / 128.0f);
        const float var  = q2 * (1.0f / 128.0f) - mean * mean;
        red2[tid][0] = mean;
        red2[tid][1] = __builtin_amdgcn_rsqf(var + 1e-5f);
    }
    __syncthreads();                              // B5: h_out + stats visible

    // ---- LN + fully coalesced store ---------------------------------------
    float* ob = out + row0 * 128;
    #pragma unroll
    for (int it = 0; it < 8; ++it) {
        const int idx = it * 256 + tid;           // float4 index, coalesced
        const int r = idx >> 5;
        const int c4 = (idx & 31) * 4;            // feature col base
        const unsigned off = (unsigned)(r * 256) + (((unsigned)(c4 * 2)) ^ SWZ(r));
        const uint2 hv = *(const uint2*)(xh + off);
        const float mean = red2[r][0], rstd = red2[r][1];
        const float4 g4 = *(const float4*)(prm + 5 * 128 + c4);
        const float4 b4 = *(const float4*)(prm + 6 * 128 + c4);
        float4 rr;
        rr.x = (lo_f16(hv.x) - mean) * rstd * g4.x + b4.x;
        rr.y = (hi_f16(hv.x) - mean) * rstd * g4.y + b4.y;
        rr.z = (lo_f16(hv.y) - mean) * rstd * g4.z + b4.z;
        rr.w = (hi_f16(hv.y) - mean) * rstd * g4.w + b4.w;
        *(float4*)(ob + (size_t)idx * 4) = rr;
    }
}

// ------------------------------- launch ------------------------------------
extern "C" void kernel_launch(void* const* d_in, const int* in_sizes, int n_in,
                              void* d_out, int out_size, void* d_ws, size_t ws_size,
                              hipStream_t stream) {
    const float* x      = (const float*)d_in[0];
    const float* h_prev = (const float*)d_in[1];
    const float* Ws_w   = (const float*)d_in[2];
    const float* Ws_b   = (const float*)d_in[3];
    const float* Wfast  = (const float*)d_in[4];
    const float* Wi_w   = (const float*)d_in[5];
    const float* Wi_b   = (const float*)d_in[6];
    const float* Wf_w   = (const float*)d_in[7];
    const float* Wf_b   = (const float*)d_in[8];
    const float* Wo_w   = (const float*)d_in[9];
    const float* Wo_b   = (const float*)d_in[10];
    const float* ln_g   = (const float*)d_in[11];
    const float* ln_b   = (const float*)d_in[12];

    unsigned short* Wshuf = (unsigned short*)d_ws;           // 65536 bf16 = 128 KB
    float*          fb    = (float*)(Wshuf + 65536);         // 128 f32

    prep_weights<<<256, 256, 0, stream>>>(Wi_w, Wf_w, Ws_w, Wfast, Wo_w, Wshuf);
    prep_fbias<<<1, 128, 0, stream>>>(Wf_w, Wf_b, h_prev, fb);

    const int B = in_sizes[0] / 128;                         // 262144
    const int blocks = B / 64;                               // 64 rows per block
    cell_main<<<blocks, 256, 0, stream>>>(x, h_prev, Wi_b, Ws_b, Wo_b,
                                          ln_g, ln_b, Wshuf, fb,
                                          (float*)d_out);
}